// Round 20
// baseline (109.423 us; speedup 1.0000x reference)
//
#include <hip/hip_runtime.h>
#include <math.h>

#define NTOK   16384
#define DIM    2048
#define NEXP   64
#define TOPK   8
#define TB     16          // tokens per block -> grid 1024
#define KC     64          // K per phase per wave
#define KHALF  1024        // K per wave (half of DIM)
#define NPHASE (KHALF / KC) // 16
#define XLS    20          // xl row stride (dwords): 80B rows, 16B-aligned reads
#define NLIMB  4

typedef int    v4i __attribute__((ext_vector_type(4)));
typedef double v4d __attribute__((ext_vector_type(4)));

// ws layout: [0,512) pinv (64 f64); [512, 512+524288) proto limb dwords
#define WS_NEEDED (512 + (size_t)NEXP * NLIMB * (DIM / 4) * 4)

#define XSCALE 134217728.0f     // 2^27 : x digits; residual <= 2^-28
#define PSCALE 8589934592.0f    // 2^33 : p digits; residual <= 2^-34
#define BIAS   0x80808080u      // per-byte +128 bias (carry-free digits)

// class-combine weights 2^(8d-60), d=0..6
__device__ __constant__ double CWD4[7] = {
    8.673617379884035e-19, 2.220446049250313e-16, 5.684341886080802e-14,
    1.4551915228366852e-11, 3.725290298461914e-09, 9.5367431640625e-07,
    2.44140625e-04};

// ---------------- pre-kernel: pinv (f64) + proto 4-limb radix-256 decomposition ----------------
__global__ __launch_bounds__(64) void proto_prep_kernel(
    const float* __restrict__ proto, double* __restrict__ pinv,
    int* __restrict__ plimb)
{
    const int e = blockIdx.x, t = threadIdx.x;
    const float* row = proto + (size_t)e * DIM;
    const int k0 = t * 32;
    double s = 0.0;
#pragma unroll
    for (int g = 0; g < 8; ++g) {
        unsigned pk0 = 0, pk1 = 0, pk2 = 0, pk3 = 0;
#pragma unroll
        for (int b = 0; b < 4; ++b) {
            float f = row[k0 + g * 4 + b];
            s += (double)f * (double)f;
            int u = (int)rintf(f * PSCALE);       // exact: pow2 scale + rndne
            unsigned ub = (unsigned)u + BIAS;     // carry-free biased digits
            pk0 |= ( ub        & 255u) << (8 * b);
            pk1 |= ((ub >>  8) & 255u) << (8 * b);
            pk2 |= ((ub >> 16) & 255u) << (8 * b);
            pk3 |= ( ub >> 24        ) << (8 * b);
        }
        const int dw = (k0 + g * 4) >> 2;
        plimb[(e * NLIMB + 0) * (DIM / 4) + dw] = (int)(pk0 ^ BIAS);
        plimb[(e * NLIMB + 1) * (DIM / 4) + dw] = (int)(pk1 ^ BIAS);
        plimb[(e * NLIMB + 2) * (DIM / 4) + dw] = (int)(pk2 ^ BIAS);
        plimb[(e * NLIMB + 3) * (DIM / 4) + dw] = (int)(pk3 ^ BIAS);
    }
#pragma unroll
    for (int d = 1; d < 64; d <<= 1)
        s += __shfl_xor(s, d, 64);
    if (t == 0)
        pinv[e] = 1.0 / fmax(sqrt(s), 1e-12);
}

#define MF(A, B, C) __builtin_amdgcn_mfma_i32_16x16x64_i8(A, B, C, 0, 0, 0)

// 16 class MFMAs (4x4 limbs, class d=i+j in 0..6), j-major (r18-verified)
#define BURST16(AF, B0, B1, B2, B3) do {                                                \
    acc[0]=MF(AF[0],B0,acc[0]); acc[1]=MF(AF[1],B0,acc[1]);                             \
    acc[2]=MF(AF[2],B0,acc[2]); acc[3]=MF(AF[3],B0,acc[3]);                             \
    acc[1]=MF(AF[0],B1,acc[1]); acc[2]=MF(AF[1],B1,acc[2]);                             \
    acc[3]=MF(AF[2],B1,acc[3]); acc[4]=MF(AF[3],B1,acc[4]);                             \
    acc[2]=MF(AF[0],B2,acc[2]); acc[3]=MF(AF[1],B2,acc[3]);                             \
    acc[4]=MF(AF[2],B2,acc[4]); acc[5]=MF(AF[3],B2,acc[5]);                             \
    acc[3]=MF(AF[0],B3,acc[3]); acc[4]=MF(AF[1],B3,acc[4]);                             \
    acc[5]=MF(AF[2],B3,acc[5]); acc[6]=MF(AF[3],B3,acc[6]);                             \
} while (0)

#define LOADAF4(cur) do {                                        \
    af[0] = *(const v4i*)&xl[cur][khalf][0][arow][akg * 4];      \
    af[1] = *(const v4i*)&xl[cur][khalf][1][arow][akg * 4];      \
    af[2] = *(const v4i*)&xl[cur][khalf][2][arow][akg * 4];      \
    af[3] = *(const v4i*)&xl[cur][khalf][3][arow][akg * 4];      \
} while (0)

#define LOADB4(c) do {                                           \
    const int* _bp = bbase + (c) * 16;                           \
    bf0 = *(const v4i*)(_bp);                                    \
    bf1 = *(const v4i*)(_bp + 1 * (DIM / 4));                    \
    bf2 = *(const v4i*)(_bp + 2 * (DIM / 4));                    \
    bf3 = *(const v4i*)(_bp + 3 * (DIM / 4));                    \
} while (0)

// ---------------- main: 8-wave i8-MFMA router, in-block K-split ----------------
__global__ __launch_bounds__(512, 6) void router_i8_kernel(
    const float* __restrict__ x, const double* __restrict__ pinv,
    const int* __restrict__ plimb, float* __restrict__ out)
{
    __shared__ __align__(16) int xl[2][2][NLIMB][TB][XLS]; // [dbuf][khalf], 20480 B
    __shared__ float  logits[TB][NEXP];                    // 4 KiB
    __shared__ double xinv_lds[TB];
    __shared__ double xpart[2][TB];
    __shared__ double pinv_lds[NEXP];

    const int tid  = threadIdx.x;
    const int lane = tid & 63;
    const int w    = tid >> 6;            // wave 0..7
    const int tok0 = blockIdx.x * TB;

    // decomp role: 4 floats/thread; 512 threads cover both K-half panels
    const int kp = tid >> 8;              // panel 0/1
    const int td = (tid >> 4) & 15;       // token
    const int dw = tid & 15;              // dword group within 64-k phase slice
    const float* xsrc = x + (size_t)(tok0 + td) * DIM + kp * KHALF + dw * 4;

    // MFMA role: wave = (etile, khalf)
    const int etile = w & 3;
    const int khalf = w >> 2;
    const int arow  = lane & 15;
    const int akg   = lane >> 4;
    const int ecol  = etile * 16 + arow;
    const int* bbase = plimb + (size_t)ecol * NLIMB * (DIM / 4)
                             + khalf * (KHALF / 4) + akg * 4;

    v4i acc[7];
#pragma unroll
    for (int d = 0; d < 7; ++d) acc[d] = (v4i){0, 0, 0, 0};
    double sumsq = 0.0;

    if (tid < NEXP) pinv_lds[tid] = pinv[tid];

    // decompose 4 floats -> 4 limb-dwords into xl[buf][kp]; fuse sumsq
    auto decomp_store = [&](const float4 xq, int buf) {
        sumsq += (double)xq.x * xq.x + (double)xq.y * xq.y
               + (double)xq.z * xq.z + (double)xq.w * xq.w;
        unsigned b0 = (unsigned)(int)rintf(xq.x * XSCALE) + BIAS;
        unsigned b1 = (unsigned)(int)rintf(xq.y * XSCALE) + BIAS;
        unsigned b2 = (unsigned)(int)rintf(xq.z * XSCALE) + BIAS;
        unsigned b3 = (unsigned)(int)rintf(xq.w * XSCALE) + BIAS;
#pragma unroll
        for (int i = 0; i < NLIMB; ++i) {
            unsigned d = ((b0 >> (8 * i)) & 255u)
                       | (((b1 >> (8 * i)) & 255u) << 8)
                       | (((b2 >> (8 * i)) & 255u) << 16)
                       | (((b3 >> (8 * i)) & 255u) << 24);
            xl[buf][kp][i][td][dw] = (int)(d ^ BIAS);
        }
    };

    // named B-limb registers, single-buffered (r17/r18 pinned pattern)
    v4i bf0, bf1, bf2, bf3;

    // ---- prologue ----
    LOADB4(0);
    float4 xv = *(const float4*)(xsrc);
    decomp_store(xv, 0);
    xv = *(const float4*)(xsrc + KC);
    asm volatile("s_waitcnt lgkmcnt(0)" ::: "memory");
    __builtin_amdgcn_sched_barrier(0);
    __builtin_amdgcn_s_barrier();

    // ---- main loop: 16 phases, pinned; raw barrier (B loads fly across) ----
    for (int c = 0; c < NPHASE; ++c) {
        const int cur = c & 1;

        v4i af[NLIMB];
        LOADAF4(cur);                                    // ds_read_b128 x4
        if (c + 1 < NPHASE) {
            decomp_store(xv, cur ^ 1);                   // VALU covers af latency
            if (c + 2 < NPHASE) xv = *(const float4*)(xsrc + (c + 2) * KC);
        }
        asm volatile("s_waitcnt lgkmcnt(0)" ::: "memory");
        __builtin_amdgcn_sched_barrier(0);               // rule #18: pin MFMA below

        __builtin_amdgcn_s_setprio(1);
        BURST16(af, bf0, bf1, bf2, bf3);                 // bf loaded a phase ago
        __builtin_amdgcn_s_setprio(0);
        __builtin_amdgcn_sched_barrier(0);               // pin LOADB after BURST

        if (c + 1 < NPHASE) LOADB4(c + 1);               // fly over barrier
        __builtin_amdgcn_sched_barrier(0);
        __builtin_amdgcn_s_barrier();                    // raw: no vmcnt drain
    }

    // ---- xinv partials: reduce 16 threads sharing (kp, td) ----
    sumsq += __shfl_xor(sumsq, 1, 16);
    sumsq += __shfl_xor(sumsq, 2, 16);
    sumsq += __shfl_xor(sumsq, 4, 16);
    sumsq += __shfl_xor(sumsq, 8, 16);
    if (dw == 0)
        xpart[kp][td] = sumsq;

    // ---- i32 layout calibration (r13-proven; cheap, all waves) ----
    const int ones = 0x01010101;
    v4i onesv = (v4i){ones, ones, ones, ones};
    int rp = arow * ones;
    v4i rowv = (v4i){rp, rp, rp, rp};
    v4i c1 = (v4i){0, 0, 0, 0}, c2 = (v4i){0, 0, 0, 0};
    c1 = __builtin_amdgcn_mfma_i32_16x16x64_i8(rowv, onesv, c1, 0, 0, 0);  // 64*row
    c2 = __builtin_amdgcn_mfma_i32_16x16x64_i8(onesv, rowv, c2, 0, 0, 0);  // 64*col

    // ---- K-half combine via LDS (aliases dead xl; i32 adds -> exact) ----
    int* cb = (int*)xl;
    if (w >= 4) {                       // stash acc[0..3] (16 dwords/lane)
        int base = ((w - 4) * 64 + lane) * 16;
#pragma unroll
        for (int d = 0; d < 4; ++d) {
            cb[base + 4 * d + 0] = acc[d][0]; cb[base + 4 * d + 1] = acc[d][1];
            cb[base + 4 * d + 2] = acc[d][2]; cb[base + 4 * d + 3] = acc[d][3];
        }
    }
    __syncthreads();
    if (w < 4) {                        // add partner's acc[0..3]
        int base = (w * 64 + lane) * 16;
#pragma unroll
        for (int d = 0; d < 4; ++d) {
            acc[d][0] += cb[base + 4 * d + 0]; acc[d][1] += cb[base + 4 * d + 1];
            acc[d][2] += cb[base + 4 * d + 2]; acc[d][3] += cb[base + 4 * d + 3];
        }
    }
    if (tid < TB)                       // finalize xinv (deterministic [0]+[1])
        xinv_lds[tid] = 1.0 / fmax(sqrt(xpart[0][tid] + xpart[1][tid]), 1e-12);
    __syncthreads();
    if (w >= 4) {                       // stash acc[4..6] (12 dwords/lane)
        int base = ((w - 4) * 64 + lane) * 12;
#pragma unroll
        for (int d = 0; d < 3; ++d) {
            cb[base + 4 * d + 0] = acc[4 + d][0]; cb[base + 4 * d + 1] = acc[4 + d][1];
            cb[base + 4 * d + 2] = acc[4 + d][2]; cb[base + 4 * d + 3] = acc[4 + d][3];
        }
    }
    __syncthreads();
    if (w < 4) {
        int base = (w * 64 + lane) * 12;
#pragma unroll
        for (int d = 0; d < 3; ++d) {
            acc[4 + d][0] += cb[base + 4 * d + 0]; acc[4 + d][1] += cb[base + 4 * d + 1];
            acc[4 + d][2] += cb[base + 4 * d + 2]; acc[4 + d][3] += cb[base + 4 * d + 3];
        }
        // ---- combine classes in f64, scale to cosine logits, cast fp32 ----
#pragma unroll
        for (int i = 0; i < 4; ++i) {
            double S = 0.0;
#pragma unroll
            for (int d = 0; d < 7; ++d)
                S = fma((double)acc[d][i], CWD4[d], S);
            const int tr = c1[i] >> 6;             // token-within-tile label
            const int ec = c2[i] >> 6;             // expert-within-16 label
            const int e  = etile * 16 + ec;
            logits[tr][e] = (float)(S * xinv_lds[tr] * pinv_lds[e]);
        }
    }
    __syncthreads();

    // ---- epilogue (waves 0-3): np fp32 softmax bit-chain + rank ----
    if (w < 4) {
#pragma unroll 1
        for (int i = 0; i < 4; ++i) {
            const int tl = w * 4 + i;
            const float l32 = logits[tl][lane];

            float m = l32;
#pragma unroll
            for (int d = 1; d < 64; d <<= 1) {
                float o = __shfl_xor(m, d, 64);
                m = fmaxf(m, o);
            }
            const float dd = l32 - m;
            const float e32 = (float)exp((double)dd);

            float r[8];
#pragma unroll
            for (int j = 0; j < 8; ++j) {
                float rj = __shfl(e32, j, 64);
#pragma unroll
                for (int b = 1; b < 8; ++b)
                    rj += __shfl(e32, j + 8 * b, 64);
                r[j] = rj;
            }
            const float S = ((r[0] + r[1]) + (r[2] + r[3])) +
                            ((r[4] + r[5]) + (r[6] + r[7]));
            const float wgt = e32 / S;

            int rank = 0;
#pragma unroll 1
            for (int sdist = 1; sdist < 64; ++sdist) {
                float ow = __shfl_xor(wgt, sdist, 64);
                int j = lane ^ sdist;
                rank += (ow > wgt) || (ow == wgt && j < lane);
            }

            if (rank < TOPK) {
                const int tok = tok0 + tl;
                out[tok * TOPK + rank] = wgt;
                out[NTOK * TOPK + tok * TOPK + rank] = (float)lane;
            }
        }
    }
}

// ---------------- fallback: proven r12 f64-MFMA kernel (ws too small) ----------------
__global__ __launch_bounds__(256, 2) void router_f64_kernel(
    const float* __restrict__ x, const float* __restrict__ proto,
    float* __restrict__ out)
{
    __shared__ float  logits[TB][NEXP];
    __shared__ double xinv_lds[TB];
    __shared__ double pinv_lds[NEXP];

    const int tid  = threadIdx.x;
    const int lane = tid & 63;
    const int w    = tid >> 6;
    const int tok0 = blockIdx.x * TB;
    const int etile = w;
    const int arow  = lane & 15;
    const int akg   = lane >> 4;
    const int kbase = akg * 8;

    v4d acc0 = {0., 0., 0., 0.}, acc1 = {0., 0., 0., 0.};
    v4d acc2 = {0., 0., 0., 0.}, acc3 = {0., 0., 0., 0.};
    double sumsq = 0.0, psq = 0.0;

    const float* xrow = x     + (size_t)(tok0 + arow)       * DIM + kbase;
    const float* prow = proto + (size_t)(etile * 16 + arow) * DIM + kbase;

    float4 xa0, xa1, pa0, pa1, xb0, xb1, pb0, pb1;

#define FLOADSET(X0, X1, P0, P1, c) do {                            \
    const float* _xp = xrow + (c) * 32;                             \
    const float* _pp = prow + (c) * 32;                             \
    X0 = *(const float4*)(_xp);  X1 = *(const float4*)(_xp + 4);    \
    P0 = *(const float4*)(_pp);  P1 = *(const float4*)(_pp + 4);    \
    } while (0)
#define FNORMQ(A, B) do {                                           \
    double a0 = (double)A.x, a1 = (double)A.y,                      \
           a2 = (double)A.z, a3 = (double)A.w;                      \
    double u0 = (double)B.x, u1 = (double)B.y,                      \
           u2 = (double)B.z, u3 = (double)B.w;                      \
    sumsq += a0*a0 + a1*a1 + a2*a2 + a3*a3;                         \
    psq   += u0*u0 + u1*u1 + u2*u2 + u3*u3;                         \
    } while (0)
#define FCOMPUTE(X0, X1, P0, P1) do {                               \
    FNORMQ(X0, P0); FNORMQ(X1, P1);                                 \
    acc0 = __builtin_amdgcn_mfma_f64_16x16x4f64((double)X0.x, (double)P0.x, acc0, 0, 0, 0); \
    acc1 = __builtin_amdgcn_mfma_f64_16x16x4f64((double)X0.y, (double)P0.y, acc1, 0, 0, 0); \
    acc2 = __builtin_amdgcn_mfma_f64_16x16x4f64((double)X0.z, (double)P0.z, acc2, 0, 0, 0); \
    acc3 = __builtin_amdgcn_mfma_f64_16x16x4f64((double)X0.w, (double)P0.w, acc3, 0, 0, 0); \
    acc0 = __builtin_amdgcn_mfma_f64_16x16x4f64((double)X1.x, (double)P1.x, acc0, 0, 0, 0); \
    acc1 = __builtin_amdgcn_mfma_f64_16x16x4f64((double)X1.y, (double)P1.y, acc1, 0, 0, 0); \
    acc2 = __builtin_amdgcn_mfma_f64_16x16x4f64((double)X1.z, (double)P1.z, acc2, 0, 0, 0); \
    acc3 = __builtin_amdgcn_mfma_f64_16x16x4f64((double)X1.w, (double)P1.w, acc3, 0, 0, 0); \
    } while (0)

    FLOADSET(xa0, xa1, pa0, pa1, 0);
    for (int c = 0; c < 64; c += 2) {
        FLOADSET(xb0, xb1, pb0, pb1, c + 1);
        FCOMPUTE(xa0, xa1, pa0, pa1);
        if (c + 2 < 64) FLOADSET(xa0, xa1, pa0, pa1, c + 2);
        FCOMPUTE(xb0, xb1, pb0, pb1);
    }
    const v4d acc = (acc0 + acc1) + (acc2 + acc3);

    sumsq += __shfl_xor(sumsq, 16, 64);
    sumsq += __shfl_xor(sumsq, 32, 64);
    psq   += __shfl_xor(psq, 16, 64);
    psq   += __shfl_xor(psq, 32, 64);
    if (akg == 0) {
        xinv_lds[arow]              = 1.0 / fmax(sqrt(sumsq), 1e-12);
        pinv_lds[etile * 16 + arow] = 1.0 / fmax(sqrt(psq), 1e-12);
    }
    v4d c1 = {0., 0., 0., 0.}, c2 = {0., 0., 0., 0.};
    c1 = __builtin_amdgcn_mfma_f64_16x16x4f64((double)arow, 1.0, c1, 0, 0, 0);
    c2 = __builtin_amdgcn_mfma_f64_16x16x4f64(1.0, (double)arow, c2, 0, 0, 0);
    __syncthreads();
#pragma unroll
    for (int i = 0; i < 4; ++i) {
        const int tr = (int)(c1[i] * 0.25);
        const int ec = (int)(c2[i] * 0.25);
        const int e  = etile * 16 + ec;
        logits[tr][e] = (float)(acc[i] * xinv_lds[tr] * pinv_lds[e]);
    }
    __syncthreads();
#pragma unroll 1
    for (int i = 0; i < 4; ++i) {
        const int tl = w * 4 + i;
        const float l32 = logits[tl][lane];
        float m = l32;
#pragma unroll
        for (int d = 1; d < 64; d <<= 1) {
            float o = __shfl_xor(m, d, 64);
            m = fmaxf(m, o);
        }
        const float dd = l32 - m;
        const float e32 = (float)exp((double)dd);
        float r[8];
#pragma unroll
        for (int j = 0; j < 8; ++j) {
            float rj = __shfl(e32, j, 64);
#pragma unroll
            for (int b = 1; b < 8; ++b)
                rj += __shfl(e32, j + 8 * b, 64);
            r[j] = rj;
        }
        const float S = ((r[0] + r[1]) + (r[2] + r[3])) +
                        ((r[4] + r[5]) + (r[6] + r[7]));
        const float wgt = e32 / S;
        int rank = 0;
#pragma unroll 1
        for (int sdist = 1; sdist < 64; ++sdist) {
            float ow = __shfl_xor(wgt, sdist, 64);
            int j = lane ^ sdist;
            rank += (ow > wgt) || (ow == wgt && j < lane);
        }
        if (rank < TOPK) {
            const int tok = tok0 + tl;
            out[tok * TOPK + rank] = wgt;
            out[NTOK * TOPK + tok * TOPK + rank] = (float)lane;
        }
    }
}

extern "C" void kernel_launch(void* const* d_in, const int* in_sizes, int n_in,
                              void* d_out, int out_size, void* d_ws, size_t ws_size,
                              hipStream_t stream) {
    const float* x     = (const float*)d_in[0];
    const float* proto = (const float*)d_in[1];
    float* out         = (float*)d_out;
    (void)in_sizes; (void)n_in; (void)out_size;

    if (ws_size >= WS_NEEDED) {
        double* pinv = (double*)d_ws;
        int*    plimb = (int*)((char*)d_ws + 512);
        proto_prep_kernel<<<NEXP, 64, 0, stream>>>(proto, pinv, plimb);
        router_i8_kernel<<<NTOK / TB, 512, 0, stream>>>(x, pinv, plimb, out);
    } else {
        router_f64_kernel<<<NTOK / TB, 256, 0, stream>>>(x, proto, out);
    }
}